// Round 2
// baseline (461.876 us; speedup 1.0000x reference)
//
#include <hip/hip_runtime.h>
#include <hip/hip_bf16.h>

#define TSEQ 2048
#define HID 384
#define NHEAD 4
#define HD 96
#define NBATCH 8

using bf16 = __bf16;
typedef bf16 bf16x8 __attribute__((ext_vector_type(8)));
typedef bf16 bf16x4 __attribute__((ext_vector_type(4)));
typedef float f32x4 __attribute__((ext_vector_type(4)));

static __device__ __forceinline__ f32x4 mfma16(bf16x8 a, bf16x8 b, f32x4 c) {
    return __builtin_amdgcn_mfma_f32_16x16x32_bf16(a, b, c, 0, 0, 0);
}

// ---------------- conversion kernels ----------------
__global__ void k_conv8(const float* __restrict__ src, bf16* __restrict__ dst, int n8) {
    int t = blockIdx.x * 256 + threadIdx.x;
    if (t >= n8) return;
    const float4* s4 = reinterpret_cast<const float4*>(src);
    float4 a = s4[2 * t], b = s4[2 * t + 1];
    bf16x8 o;
    o[0] = (bf16)a.x; o[1] = (bf16)a.y; o[2] = (bf16)a.z; o[3] = (bf16)a.w;
    o[4] = (bf16)b.x; o[5] = (bf16)b.y; o[6] = (bf16)b.z; o[7] = (bf16)b.w;
    *reinterpret_cast<bf16x8*>(dst + 8 * t) = o;
}

__global__ void k_convT(const float* __restrict__ W, bf16* __restrict__ WT) {
    int t = blockIdx.x * 256 + threadIdx.x;  // WT[n][k] = W[k][n]
    int n = t / HID, k = t % HID;
    WT[t] = (bf16)W[(size_t)k * HID + n];
}

// ---------------- projection GEMM (Q,K,V,pos) ----------------
__launch_bounds__(256, 2)
__global__ void k_proj(const bf16* __restrict__ X, const bf16* __restrict__ P,
                       const bf16* __restrict__ wqT, const bf16* __restrict__ wkT,
                       const bf16* __restrict__ wvT, const bf16* __restrict__ wpT,
                       const float* __restrict__ bq, const float* __restrict__ bk,
                       const float* __restrict__ bv,
                       const float* __restrict__ pbu, const float* __restrict__ pbv,
                       bf16* __restrict__ qu, bf16* __restrict__ qv,
                       bf16* __restrict__ kws, bf16* __restrict__ vt,
                       bf16* __restrict__ pp) {
    __shared__ bf16 wt_lds[96][392];
    const float SC = 0.10206207262f;  // 1/sqrt(96) folded into q
    int mat = blockIdx.z;             // 0=Q 1=K 2=V 3=POS
    int m0 = blockIdx.x * 64;
    if (mat == 3 && m0 >= 4095) return;
    int n0 = blockIdx.y * 96;
    const bf16* A  = (mat == 3) ? P : X;
    const bf16* WT = (mat == 0) ? wqT : (mat == 1) ? wkT : (mat == 2) ? wvT : wpT;
    int tid = threadIdx.x;
    #pragma unroll
    for (int s = 0; s < 18; ++s) {
        int cc = tid + 256 * s;
        int r = cc / 48, ch = cc % 48;
        *reinterpret_cast<int4*>(&wt_lds[r][ch * 8]) =
            *reinterpret_cast<const int4*>(WT + (size_t)(n0 + r) * HID + ch * 8);
    }
    __syncthreads();
    int lane = tid & 63, w = tid >> 6;
    int c = lane & 15, g = lane >> 4;
    int arow = m0 + 16 * w + c;
    if (mat == 3 && arow > 4095) arow = 4095;
    const bf16* Abase = A + (size_t)arow * HID + 8 * g;
    f32x4 acc[6] = {};
    for (int ks = 0; ks < 12; ++ks) {
        bf16x8 a = *reinterpret_cast<const bf16x8*>(Abase + 32 * ks);
        #pragma unroll
        for (int jt = 0; jt < 6; ++jt) {
            bf16x8 b = *reinterpret_cast<const bf16x8*>(&wt_lds[16 * jt + c][32 * ks + 8 * g]);
            acc[jt] = mfma16(a, b, acc[jt]);
        }
    }
    int h = blockIdx.y;
    int rbase = m0 + 16 * w + 4 * g;
    if (mat == 0) {
        #pragma unroll
        for (int jt = 0; jt < 6; ++jt) {
            int n = n0 + 16 * jt + c;
            int d = 16 * jt + c;
            float bb = bq[n], bu = pbu[n], bvv = pbv[n];
            #pragma unroll
            for (int j = 0; j < 4; ++j) {
                int m = rbase + j;
                int b_ = m >> 11, t = m & 2047;
                size_t o = (((size_t)(b_ * NHEAD + h)) * TSEQ + t) * HD + d;
                float q = acc[jt][j] + bb;
                qu[o] = (bf16)((q + bu) * SC);
                qv[o] = (bf16)((q + bvv) * SC);
            }
        }
    } else if (mat == 1) {
        #pragma unroll
        for (int jt = 0; jt < 6; ++jt) {
            int n = n0 + 16 * jt + c;
            int d = 16 * jt + c;
            float bb = bk[n];
            #pragma unroll
            for (int j = 0; j < 4; ++j) {
                int m = rbase + j;
                int b_ = m >> 11, t = m & 2047;
                size_t o = (((size_t)(b_ * NHEAD + h)) * TSEQ + t) * HD + d;
                kws[o] = (bf16)(acc[jt][j] + bb);
            }
        }
    } else if (mat == 2) {
        #pragma unroll
        for (int jt = 0; jt < 6; ++jt) {
            int d = 16 * jt + c;
            float bb = bv[n0 + 16 * jt + c];
            int m = rbase;
            int b_ = m >> 11, t0 = m & 2047;
            size_t o = (((size_t)(b_ * NHEAD + h)) * HD + d) * TSEQ + t0;
            bf16x4 pk;
            #pragma unroll
            for (int j = 0; j < 4; ++j) pk[j] = (bf16)(acc[jt][j] + bb);
            *reinterpret_cast<bf16x4*>(vt + o) = pk;
        }
    } else {
        #pragma unroll
        for (int jt = 0; jt < 6; ++jt) {
            int d = 16 * jt + c;
            #pragma unroll
            for (int j = 0; j < 4; ++j) {
                int m = rbase + j;
                if (m < 4095) {
                    size_t o = ((size_t)h * 4096 + m) * HD + d;
                    pp[o] = (bf16)acc[jt][j];
                }
            }
        }
    }
}

// ---------------- fused rel-pos flash attention (transposed-S) ----------------
// grid 1024 blocks (XCD-swizzled), 256 threads = 4 waves, wave owns 16 q-rows.
// S^T = mfma(K,Qu): lane(c,g) reg(t,j) holds S^T[k=16t+4g+j][q=c].
__launch_bounds__(256, 2)
__global__ void k_attn(const bf16* __restrict__ qu, const bf16* __restrict__ qv,
                       const bf16* __restrict__ kws, const bf16* __restrict__ vt,
                       const bf16* __restrict__ pp, const int* __restrict__ mask,
                       bf16* __restrict__ out) {
    __shared__ bf16 k_lds[64][104];
    __shared__ bf16 pos_lds[128][104];    // ring, slot = n & 127
    __shared__ bf16 vt_lds[96][64];       // 16B-chunk XOR swizzle
    __shared__ bf16 win_lds[4][16][104];  // per-wave W^T col-major, skew c+1
    __shared__ bf16 p_lds[4][16][72];     // per-wave P[q][k]
    __shared__ float msk_lds[64];

    int bid = blockIdx.x;
    int v  = (bid & 7) * 128 + (bid >> 3);  // XCD swizzle (1024 % 8 == 0)
    int qb = v & 31, bh = v >> 5;
    int q0 = qb * 64;
    int b_ = bh >> 2, h = bh & 3;

    int tid = threadIdx.x, lane = tid & 63, w = tid >> 6;
    int c = lane & 15, g = lane >> 4;
    const int n_base0 = TSEQ - 1 - 63 - q0;  // lowest pos row for kt=0
    const float L2E = 1.44269504089f;
    int sw = 48 - 16 * w;                    // wave's window start offset

    bf16x8 qu_f[3], qv_f[3];
    {
        size_t rowbase = ((size_t)bh * TSEQ + q0 + 16 * w + c) * HD + 8 * g;
        #pragma unroll
        for (int ds = 0; ds < 3; ++ds) {
            qu_f[ds] = *reinterpret_cast<const bf16x8*>(qu + rowbase + 32 * ds);
            qv_f[ds] = *reinterpret_cast<const bf16x8*>(qv + rowbase + 32 * ds);
        }
    }

    f32x4 acc_o[6] = {};
    float mrow = -3.0e38f, lrow = 0.f;

    // ---- prologue: stage kt=0 tile ----
    {
        const bf16* kb = kws + (size_t)bh * TSEQ * HD;
        const bf16* vb = vt + (size_t)bh * HD * TSEQ;
        const bf16* pb = pp + (size_t)h * 4096 * HD;
        #pragma unroll
        for (int s = 0; s < 3; ++s) {
            int cc = tid + 256 * s; int r = cc / 12, ch = cc % 12;
            *reinterpret_cast<int4*>(&k_lds[r][ch * 8]) =
                *reinterpret_cast<const int4*>(kb + (size_t)r * HD + ch * 8);
        }
        #pragma unroll
        for (int s = 0; s < 3; ++s) {
            int cc = tid + 256 * s; int r = cc >> 3, ch = cc & 7;
            int4 vv = *reinterpret_cast<const int4*>(vb + (size_t)r * TSEQ + ch * 8);
            *reinterpret_cast<int4*>(&vt_lds[r][((ch ^ (r & 7)) * 8)]) = vv;
        }
        #pragma unroll
        for (int s = 0; s < 6; ++s) {
            int cc = tid + 256 * s; int r = cc / 12, ch = cc % 12;
            int n = n_base0 + r;
            *reinterpret_cast<int4*>(&pos_lds[n & 127][ch * 8]) =
                *reinterpret_cast<const int4*>(pb + (size_t)n * HD + ch * 8);
        }
        if (tid < 64) msk_lds[tid] = (mask[b_ * TSEQ + tid] == 0) ? -1e30f : 0.f;
    }
    __syncthreads();

    for (int kt = 0; kt < 32; ++kt) {
        bool pre = kt < 31;
        // ---- T14: issue next-tile global loads early ----
        int4 rK[3], rV[3], rP[3]; int rM = 0;
        int r_[3], ch_[3], rv_[3], cv_[3], np_[3], cp_[3];
        if (pre) {
            int k0n = (kt + 1) * 64;
            const bf16* kb = kws + ((size_t)bh * TSEQ + k0n) * HD;
            const bf16* vb = vt + (size_t)bh * HD * TSEQ + k0n;
            const bf16* pb = pp + (size_t)h * 4096 * HD;
            int nst = n_base0 + 64 * kt + 127;
            #pragma unroll
            for (int s = 0; s < 3; ++s) {
                int cc = tid + 256 * s;
                r_[s] = cc / 12; ch_[s] = cc % 12;
                rK[s] = *reinterpret_cast<const int4*>(kb + (size_t)r_[s] * HD + ch_[s] * 8);
                rv_[s] = cc >> 3; cv_[s] = cc & 7;
                rV[s] = *reinterpret_cast<const int4*>(vb + (size_t)rv_[s] * TSEQ + cv_[s] * 8);
                np_[s] = nst + cc / 12; cp_[s] = cc % 12;
                rP[s] = *reinterpret_cast<const int4*>(pb + (size_t)np_[s] * HD + cp_[s] * 8);
            }
            if (tid < 64) rM = mask[b_ * TSEQ + k0n + tid];
        }

        // ---- content scores S^T ----
        f32x4 acc_s[4] = {};
        #pragma unroll
        for (int ds = 0; ds < 3; ++ds) {
            #pragma unroll
            for (int t = 0; t < 4; ++t) {
                bf16x8 a = *reinterpret_cast<const bf16x8*>(&k_lds[16 * t + c][32 * ds + 8 * g]);
                acc_s[t] = mfma16(a, qu_f[ds], acc_s[t]);
            }
        }
        // ---- rel-pos window W^T ----
        f32x4 acc_w[5] = {};
        int wbase = n_base0 + 64 * kt + sw;
        #pragma unroll
        for (int ds = 0; ds < 3; ++ds) {
            #pragma unroll
            for (int t = 0; t < 5; ++t) {
                bf16x8 a = *reinterpret_cast<const bf16x8*>(
                    &pos_lds[(wbase + 16 * t + c) & 127][32 * ds + 8 * g]);
                acc_w[t] = mfma16(a, qv_f[ds], acc_w[t]);
            }
        }
        // spill W^T column-major with skew c+1 (reads become aligned b64)
        #pragma unroll
        for (int t = 0; t < 5; ++t)
            #pragma unroll
            for (int j = 0; j < 4; ++j)
                win_lds[w][c][16 * t + 4 * g + j + c + 1] = (bf16)acc_w[t][j];
        __threadfence_block();

        // ---- assemble + online softmax (per-lane row q=c) ----
        float sA[4][4];
        #pragma unroll
        for (int t = 0; t < 4; ++t) {
            bf16x4 wv = *reinterpret_cast<const bf16x4*>(&win_lds[w][c][16 * t + 4 * g + 16]);
            float4 mv = *reinterpret_cast<const float4*>(&msk_lds[16 * t + 4 * g]);
            sA[t][0] = acc_s[t][0] + (float)wv[0] + mv.x;
            sA[t][1] = acc_s[t][1] + (float)wv[1] + mv.y;
            sA[t][2] = acc_s[t][2] + (float)wv[2] + mv.z;
            sA[t][3] = acc_s[t][3] + (float)wv[3] + mv.w;
        }
        float pm = sA[0][0];
        #pragma unroll
        for (int t = 0; t < 4; ++t)
            #pragma unroll
            for (int j = 0; j < 4; ++j) pm = fmaxf(pm, sA[t][j]);
        pm = fmaxf(pm, __shfl_xor(pm, 16));
        pm = fmaxf(pm, __shfl_xor(pm, 32));
        if (!__all(pm <= mrow + 8.0f)) {   // defer-max (THR=8)
            float mnew = fmaxf(mrow, pm);
            float alpha = exp2f((mrow - mnew) * L2E);
            mrow = mnew; lrow *= alpha;
            #pragma unroll
            for (int ot = 0; ot < 6; ++ot) acc_o[ot] *= alpha;
        }
        float rs = 0.f;
        #pragma unroll
        for (int t = 0; t < 4; ++t)
            #pragma unroll
            for (int j = 0; j < 4; ++j) {
                float p = exp2f((sA[t][j] - mrow) * L2E);
                sA[t][j] = p; rs += p;
            }
        rs += __shfl_xor(rs, 16);
        rs += __shfl_xor(rs, 32);
        lrow += rs;

        // ---- P -> LDS (col-major [q][k], aligned b64) ----
        #pragma unroll
        for (int t = 0; t < 4; ++t) {
            bf16x4 pk;
            #pragma unroll
            for (int j = 0; j < 4; ++j) pk[j] = (bf16)sA[t][j];
            *reinterpret_cast<bf16x4*>(&p_lds[w][c][16 * t + 4 * g]) = pk;
        }
        __threadfence_block();
        // ---- PV: O^T += V^T . P ----
        #pragma unroll
        for (int ds = 0; ds < 2; ++ds) {
            bf16x8 pb_ = *reinterpret_cast<const bf16x8*>(&p_lds[w][c][32 * ds + 8 * g]);
            #pragma unroll
            for (int ot = 0; ot < 6; ++ot) {
                int rr = 16 * ot + c;
                bf16x8 a = *reinterpret_cast<const bf16x8*>(
                    &vt_lds[rr][((4 * ds + g) ^ (rr & 7)) * 8]);
                acc_o[ot] = mfma16(a, pb_, acc_o[ot]);
            }
        }

        __syncthreads();   // all waves done reading this tile's LDS
        if (pre) {
            #pragma unroll
            for (int s = 0; s < 3; ++s) {
                *reinterpret_cast<int4*>(&k_lds[r_[s]][ch_[s] * 8]) = rK[s];
                *reinterpret_cast<int4*>(&vt_lds[rv_[s]][((cv_[s] ^ (rv_[s] & 7)) * 8)]) = rV[s];
                *reinterpret_cast<int4*>(&pos_lds[np_[s] & 127][cp_[s] * 8]) = rP[s];
            }
            if (tid < 64) msk_lds[tid] = (rM == 0) ? -1e30f : 0.f;
        }
        __syncthreads();
    }

    // ---- epilogue ----
    float inv = 1.0f / lrow;
    size_t m = (size_t)b_ * TSEQ + q0 + 16 * w + c;
    bf16* ob = out + m * HID + h * HD + 4 * g;
    #pragma unroll
    for (int ot = 0; ot < 6; ++ot) {
        bf16x4 pk;
        #pragma unroll
        for (int j = 0; j < 4; ++j) pk[j] = (bf16)(acc_o[ot][j] * inv);
        *reinterpret_cast<bf16x4*>(&ob[16 * ot]) = pk;
    }
}

// ---------------- output projection ----------------
__launch_bounds__(256, 2)
__global__ void k_oproj(const bf16* __restrict__ A, const bf16* __restrict__ WT,
                        const float* __restrict__ bias, float* __restrict__ out) {
    __shared__ bf16 wt_lds[96][392];
    int m0 = blockIdx.x * 64, n0 = blockIdx.y * 96;
    int tid = threadIdx.x;
    #pragma unroll
    for (int s = 0; s < 18; ++s) {
        int cc = tid + 256 * s;
        int r = cc / 48, ch = cc % 48;
        *reinterpret_cast<int4*>(&wt_lds[r][ch * 8]) =
            *reinterpret_cast<const int4*>(WT + (size_t)(n0 + r) * HID + ch * 8);
    }
    __syncthreads();
    int lane = tid & 63, w = tid >> 6;
    int c = lane & 15, g = lane >> 4;
    const bf16* Abase = A + (size_t)(m0 + 16 * w + c) * HID + 8 * g;
    f32x4 acc[6] = {};
    for (int ks = 0; ks < 12; ++ks) {
        bf16x8 a = *reinterpret_cast<const bf16x8*>(Abase + 32 * ks);
        #pragma unroll
        for (int jt = 0; jt < 6; ++jt) {
            bf16x8 b = *reinterpret_cast<const bf16x8*>(&wt_lds[16 * jt + c][32 * ks + 8 * g]);
            acc[jt] = mfma16(a, b, acc[jt]);
        }
    }
    int rbase = m0 + 16 * w + 4 * g;
    #pragma unroll
    for (int jt = 0; jt < 6; ++jt) {
        int n = n0 + 16 * jt + c;
        float bb = bias[n];
        #pragma unroll
        for (int j = 0; j < 4; ++j)
            out[(size_t)(rbase + j) * HID + n] = acc[jt][j] + bb;
    }
}

extern "C" void kernel_launch(void* const* d_in, const int* in_sizes, int n_in,
                              void* d_out, int out_size, void* d_ws, size_t ws_size,
                              hipStream_t stream) {
    const float* hs  = (const float*)d_in[0];
    const float* pe  = (const float*)d_in[1];
    const int*   msk = (const int*)d_in[2];
    const float* Wq  = (const float*)d_in[3];
    const float* bq  = (const float*)d_in[4];
    const float* Wk  = (const float*)d_in[5];
    const float* bk  = (const float*)d_in[6];
    const float* Wv  = (const float*)d_in[7];
    const float* bv  = (const float*)d_in[8];
    const float* Wo  = (const float*)d_in[9];
    const float* bo  = (const float*)d_in[10];
    const float* Wp  = (const float*)d_in[11];
    const float* pbu = (const float*)d_in[12];
    const float* pbv = (const float*)d_in[13];

    char* ws = (char*)d_ws;
    size_t off = 0;
    auto alloc = [&](size_t b) { char* p = ws + off; off += (b + 255) & ~(size_t)255; return p; };
    bf16* Xb  = (bf16*)alloc((size_t)16384 * HID * 2);
    bf16* Pb  = (bf16*)alloc((size_t)4096 * HID * 2);
    bf16* wqT = (bf16*)alloc((size_t)HID * HID * 2);
    bf16* wkT = (bf16*)alloc((size_t)HID * HID * 2);
    bf16* wvT = (bf16*)alloc((size_t)HID * HID * 2);
    bf16* woT = (bf16*)alloc((size_t)HID * HID * 2);
    bf16* wpT = (bf16*)alloc((size_t)HID * HID * 2);
    bf16* qu  = (bf16*)alloc((size_t)NBATCH * NHEAD * TSEQ * HD * 2);
    bf16* qv  = (bf16*)alloc((size_t)NBATCH * NHEAD * TSEQ * HD * 2);
    bf16* kws = (bf16*)alloc((size_t)NBATCH * NHEAD * TSEQ * HD * 2);
    bf16* vt  = (bf16*)alloc((size_t)NBATCH * NHEAD * TSEQ * HD * 2);
    bf16* pp  = (bf16*)alloc((size_t)NHEAD * 4096 * HD * 2);
    bf16* ao  = (bf16*)alloc((size_t)16384 * HID * 2);

    k_conv8<<<3072, 256, 0, stream>>>(hs, Xb, 786432);
    k_conv8<<<768, 256, 0, stream>>>(pe, Pb, 196560);
    k_convT<<<576, 256, 0, stream>>>(Wq, wqT);
    k_convT<<<576, 256, 0, stream>>>(Wk, wkT);
    k_convT<<<576, 256, 0, stream>>>(Wv, wvT);
    k_convT<<<576, 256, 0, stream>>>(Wo, woT);
    k_convT<<<576, 256, 0, stream>>>(Wp, wpT);
    k_proj<<<dim3(256, 4, 4), 256, 0, stream>>>(Xb, Pb, wqT, wkT, wvT, wpT,
                                                bq, bk, bv, pbu, pbv,
                                                qu, qv, kws, vt, pp);
    k_attn<<<1024, 256, 0, stream>>>(qu, qv, kws, vt, pp, msk, ao);
    k_oproj<<<dim3(256, 4), 256, 0, stream>>>(ao, woT, bo, (float*)d_out);
}

// Round 3
// 291.378 us; speedup vs baseline: 1.5851x; 1.5851x over previous
//
#include <hip/hip_runtime.h>
#include <hip/hip_bf16.h>

#define TSEQ 2048
#define HID 384
#define NHEAD 4
#define HD 96
#define NBATCH 8

using bf16 = __bf16;
typedef bf16 bf16x8 __attribute__((ext_vector_type(8)));
typedef bf16 bf16x4 __attribute__((ext_vector_type(4)));
typedef float f32x4 __attribute__((ext_vector_type(4)));

static __device__ __forceinline__ f32x4 mfma16(bf16x8 a, bf16x8 b, f32x4 c) {
    return __builtin_amdgcn_mfma_f32_16x16x32_bf16(a, b, c, 0, 0, 0);
}

// ---------------- conversion kernels ----------------
__global__ void k_conv8(const float* __restrict__ src, bf16* __restrict__ dst, int n8) {
    int t = blockIdx.x * 256 + threadIdx.x;
    if (t >= n8) return;
    const float4* s4 = reinterpret_cast<const float4*>(src);
    float4 a = s4[2 * t], b = s4[2 * t + 1];
    bf16x8 o;
    o[0] = (bf16)a.x; o[1] = (bf16)a.y; o[2] = (bf16)a.z; o[3] = (bf16)a.w;
    o[4] = (bf16)b.x; o[5] = (bf16)b.y; o[6] = (bf16)b.z; o[7] = (bf16)b.w;
    *reinterpret_cast<bf16x8*>(dst + 8 * t) = o;
}

__global__ void k_convT(const float* __restrict__ W, bf16* __restrict__ WT) {
    int t = blockIdx.x * 256 + threadIdx.x;  // WT[n][k] = W[k][n]
    int n = t / HID, k = t % HID;
    WT[t] = (bf16)W[(size_t)k * HID + n];
}

// ---------------- projection GEMM (Q,K,V,pos) ----------------
__launch_bounds__(256, 2)
__global__ void k_proj(const bf16* __restrict__ X, const bf16* __restrict__ P,
                       const bf16* __restrict__ wqT, const bf16* __restrict__ wkT,
                       const bf16* __restrict__ wvT, const bf16* __restrict__ wpT,
                       const float* __restrict__ bq, const float* __restrict__ bk,
                       const float* __restrict__ bv,
                       const float* __restrict__ pbu, const float* __restrict__ pbv,
                       bf16* __restrict__ qu, bf16* __restrict__ qv,
                       bf16* __restrict__ kws, bf16* __restrict__ vt,
                       bf16* __restrict__ pp) {
    __shared__ bf16 wt_lds[96][392];
    const float SC = 0.10206207262f;  // 1/sqrt(96) folded into q
    int mat = blockIdx.z;             // 0=Q 1=K 2=V 3=POS
    int m0 = blockIdx.x * 64;
    if (mat == 3 && m0 >= 4095) return;
    int n0 = blockIdx.y * 96;
    const bf16* A  = (mat == 3) ? P : X;
    const bf16* WT = (mat == 0) ? wqT : (mat == 1) ? wkT : (mat == 2) ? wvT : wpT;
    int tid = threadIdx.x;
    #pragma unroll
    for (int s = 0; s < 18; ++s) {
        int cc = tid + 256 * s;
        int r = cc / 48, ch = cc % 48;
        *reinterpret_cast<int4*>(&wt_lds[r][ch * 8]) =
            *reinterpret_cast<const int4*>(WT + (size_t)(n0 + r) * HID + ch * 8);
    }
    __syncthreads();
    int lane = tid & 63, w = tid >> 6;
    int c = lane & 15, g = lane >> 4;
    int arow = m0 + 16 * w + c;
    if (mat == 3 && arow > 4095) arow = 4095;
    const bf16* Abase = A + (size_t)arow * HID + 8 * g;
    f32x4 acc[6] = {};
    for (int ks = 0; ks < 12; ++ks) {
        bf16x8 a = *reinterpret_cast<const bf16x8*>(Abase + 32 * ks);
        #pragma unroll
        for (int jt = 0; jt < 6; ++jt) {
            bf16x8 b = *reinterpret_cast<const bf16x8*>(&wt_lds[16 * jt + c][32 * ks + 8 * g]);
            acc[jt] = mfma16(a, b, acc[jt]);
        }
    }
    int h = blockIdx.y;
    int rbase = m0 + 16 * w + 4 * g;
    if (mat == 0) {
        #pragma unroll
        for (int jt = 0; jt < 6; ++jt) {
            int n = n0 + 16 * jt + c;
            int d = 16 * jt + c;
            float bb = bq[n], bu = pbu[n], bvv = pbv[n];
            #pragma unroll
            for (int j = 0; j < 4; ++j) {
                int m = rbase + j;
                int b_ = m >> 11, t = m & 2047;
                size_t o = (((size_t)(b_ * NHEAD + h)) * TSEQ + t) * HD + d;
                float q = acc[jt][j] + bb;
                qu[o] = (bf16)((q + bu) * SC);
                qv[o] = (bf16)((q + bvv) * SC);
            }
        }
    } else if (mat == 1) {
        #pragma unroll
        for (int jt = 0; jt < 6; ++jt) {
            int n = n0 + 16 * jt + c;
            int d = 16 * jt + c;
            float bb = bk[n];
            #pragma unroll
            for (int j = 0; j < 4; ++j) {
                int m = rbase + j;
                int b_ = m >> 11, t = m & 2047;
                size_t o = (((size_t)(b_ * NHEAD + h)) * TSEQ + t) * HD + d;
                kws[o] = (bf16)(acc[jt][j] + bb);
            }
        }
    } else if (mat == 2) {
        #pragma unroll
        for (int jt = 0; jt < 6; ++jt) {
            int d = 16 * jt + c;
            float bb = bv[n0 + 16 * jt + c];
            int m = rbase;
            int b_ = m >> 11, t0 = m & 2047;
            size_t o = (((size_t)(b_ * NHEAD + h)) * HD + d) * TSEQ + t0;
            bf16x4 pk;
            #pragma unroll
            for (int j = 0; j < 4; ++j) pk[j] = (bf16)(acc[jt][j] + bb);
            *reinterpret_cast<bf16x4*>(vt + o) = pk;
        }
    } else {
        #pragma unroll
        for (int jt = 0; jt < 6; ++jt) {
            int d = 16 * jt + c;
            #pragma unroll
            for (int j = 0; j < 4; ++j) {
                int m = rbase + j;
                if (m < 4095) {
                    size_t o = ((size_t)h * 4096 + m) * HD + d;
                    pp[o] = (bf16)acc[jt][j];
                }
            }
        }
    }
}

// ---------------- fused rel-pos flash attention (transposed-S) ----------------
// grid 1024 blocks (XCD-swizzled), 256 threads = 4 waves, wave owns 16 q-rows.
// S^T = mfma(K,Qu): lane(c,g) reg(t,j) holds S^T[k=16t+4g+j][q=c].
__launch_bounds__(256, 2)
__global__ void k_attn(const bf16* __restrict__ qu, const bf16* __restrict__ qv,
                       const bf16* __restrict__ kws, const bf16* __restrict__ vt,
                       const bf16* __restrict__ pp, const int* __restrict__ mask,
                       bf16* __restrict__ out) {
    __shared__ bf16 k_lds[64][104];
    __shared__ bf16 pos_lds[128][104];    // ring, slot = n & 127
    __shared__ bf16 vt_lds[96][64];       // 16B-chunk XOR swizzle
    __shared__ bf16 win_lds[4][16][104];  // per-wave W^T col-major, skew c+1
    __shared__ bf16 p_lds[4][16][72];     // per-wave P[q][k]
    __shared__ float msk_lds[64];

    int bid = blockIdx.x;
    int v  = (bid & 7) * 128 + (bid >> 3);  // XCD swizzle (1024 % 8 == 0)
    int qb = v & 31, bh = v >> 5;
    int q0 = qb * 64;
    int b_ = bh >> 2, h = bh & 3;

    int tid = threadIdx.x, lane = tid & 63, w = tid >> 6;
    int c = lane & 15, g = lane >> 4;
    const int n_base0 = TSEQ - 1 - 63 - q0;  // lowest pos row for kt=0
    const float L2E = 1.44269504089f;
    int sw = 48 - 16 * w;                    // wave's window start offset

    // ---- kt-invariant staging coordinates (all named scalars, no arrays) ----
    int cc0 = tid, cc1 = tid + 256, cc2 = tid + 512;
    int kr0 = cc0 / 12, kc0 = cc0 % 12;
    int kr1 = cc1 / 12, kc1 = cc1 % 12;
    int kr2 = cc2 / 12, kc2 = cc2 % 12;
    int vr0 = cc0 >> 3, vc0 = cc0 & 7;
    int vr1 = cc1 >> 3, vc1 = cc1 & 7;
    int vr2 = cc2 >> 3, vc2 = cc2 & 7;
    int kO0 = kr0 * HD + kc0 * 8, kO1 = kr1 * HD + kc1 * 8, kO2 = kr2 * HD + kc2 * 8;
    int vO0 = vr0 * TSEQ + vc0 * 8, vO1 = vr1 * TSEQ + vc1 * 8, vO2 = vr2 * TSEQ + vc2 * 8;
    bf16* kP0 = &k_lds[kr0][kc0 * 8];
    bf16* kP1 = &k_lds[kr1][kc1 * 8];
    bf16* kP2 = &k_lds[kr2][kc2 * 8];
    bf16* vP0 = &vt_lds[vr0][(vc0 ^ (vr0 & 7)) * 8];
    bf16* vP1 = &vt_lds[vr1][(vc1 ^ (vr1 & 7)) * 8];
    bf16* vP2 = &vt_lds[vr2][(vc2 ^ (vr2 & 7)) * 8];
    int prow0 = n_base0 + 127 + kr0;          // prefetch pos rows (+64*kt)
    int prow1 = n_base0 + 127 + kr1;
    int prow2 = n_base0 + 127 + kr2;
    int pO0 = prow0 * HD + kc0 * 8, pO1 = prow1 * HD + kc1 * 8, pO2 = prow2 * HD + kc2 * 8;
    bf16* pPA0 = &pos_lds[prow0 & 127][kc0 * 8];
    bf16* pPA1 = &pos_lds[prow1 & 127][kc1 * 8];
    bf16* pPA2 = &pos_lds[prow2 & 127][kc2 * 8];
    bf16* pPB0 = &pos_lds[(prow0 + 64) & 127][kc0 * 8];
    bf16* pPB1 = &pos_lds[(prow1 + 64) & 127][kc1 * 8];
    bf16* pPB2 = &pos_lds[(prow2 + 64) & 127][kc2 * 8];

    const bf16* kbP = kws + (size_t)bh * TSEQ * HD;
    const bf16* vbP = vt + (size_t)bh * HD * TSEQ;
    const bf16* pbP = pp + (size_t)h * 4096 * HD;
    const int*  mbP = mask + b_ * TSEQ;

    bf16x8 qu_f[3], qv_f[3];
    {
        size_t rowbase = ((size_t)bh * TSEQ + q0 + 16 * w + c) * HD + 8 * g;
        #pragma unroll
        for (int ds = 0; ds < 3; ++ds) {
            qu_f[ds] = *reinterpret_cast<const bf16x8*>(qu + rowbase + 32 * ds);
            qv_f[ds] = *reinterpret_cast<const bf16x8*>(qv + rowbase + 32 * ds);
        }
    }

    f32x4 acc_o[6] = {};
    float mrow = -3.0e38f, lrow = 0.f;

    // ---- prologue: stage kt=0 tile + 128 pos rows + mask ----
    {
        *reinterpret_cast<int4*>(kP0) = *reinterpret_cast<const int4*>(kbP + kO0);
        *reinterpret_cast<int4*>(kP1) = *reinterpret_cast<const int4*>(kbP + kO1);
        *reinterpret_cast<int4*>(kP2) = *reinterpret_cast<const int4*>(kbP + kO2);
        *reinterpret_cast<int4*>(vP0) = *reinterpret_cast<const int4*>(vbP + vO0);
        *reinterpret_cast<int4*>(vP1) = *reinterpret_cast<const int4*>(vbP + vO1);
        *reinterpret_cast<int4*>(vP2) = *reinterpret_cast<const int4*>(vbP + vO2);
        #pragma unroll
        for (int s = 0; s < 6; ++s) {
            int cc = tid + 256 * s; int r = cc / 12, ch = cc % 12;
            int n = n_base0 + r;
            *reinterpret_cast<int4*>(&pos_lds[n & 127][ch * 8]) =
                *reinterpret_cast<const int4*>(pbP + (size_t)n * HD + ch * 8);
        }
        if (tid < 64) msk_lds[tid] = (mbP[tid] == 0) ? -1e30f : 0.f;
    }
    __syncthreads();

    for (int kt = 0; kt < 32; ++kt) {
        // ---- T14 prefetch: named scalars only (no spillable arrays) ----
        int mclamp = (kt < 31) ? (kt + 1) * 64 : 31 * 64;  // tail re-reads tile 31
        const bf16* kb = kbP + (size_t)mclamp * HD;
        const bf16* vb = vbP + mclamp;
        const bf16* pb = pbP + (size_t)(64 * kt) * HD;
        int4 fK0 = *reinterpret_cast<const int4*>(kb + kO0);
        int4 fK1 = *reinterpret_cast<const int4*>(kb + kO1);
        int4 fK2 = *reinterpret_cast<const int4*>(kb + kO2);
        int4 fV0 = *reinterpret_cast<const int4*>(vb + vO0);
        int4 fV1 = *reinterpret_cast<const int4*>(vb + vO1);
        int4 fV2 = *reinterpret_cast<const int4*>(vb + vO2);
        int4 fP0 = *reinterpret_cast<const int4*>(pb + pO0);
        int4 fP1 = *reinterpret_cast<const int4*>(pb + pO1);
        int4 fP2 = *reinterpret_cast<const int4*>(pb + pO2);
        int  fM  = mbP[mclamp + lane];

        // ---- content scores S^T ----
        __builtin_amdgcn_s_setprio(1);
        f32x4 acc_s[4] = {};
        #pragma unroll
        for (int ds = 0; ds < 3; ++ds) {
            #pragma unroll
            for (int t = 0; t < 4; ++t) {
                bf16x8 a = *reinterpret_cast<const bf16x8*>(&k_lds[16 * t + c][32 * ds + 8 * g]);
                acc_s[t] = mfma16(a, qu_f[ds], acc_s[t]);
            }
        }
        // ---- rel-pos window W^T ----
        f32x4 acc_w[5] = {};
        int wbase = n_base0 + 64 * kt + sw;
        #pragma unroll
        for (int ds = 0; ds < 3; ++ds) {
            #pragma unroll
            for (int t = 0; t < 5; ++t) {
                bf16x8 a = *reinterpret_cast<const bf16x8*>(
                    &pos_lds[(wbase + 16 * t + c) & 127][32 * ds + 8 * g]);
                acc_w[t] = mfma16(a, qv_f[ds], acc_w[t]);
            }
        }
        __builtin_amdgcn_s_setprio(0);
        // spill W^T column-major with skew c+1 (reads become aligned b64)
        #pragma unroll
        for (int t = 0; t < 5; ++t)
            #pragma unroll
            for (int j = 0; j < 4; ++j)
                win_lds[w][c][16 * t + 4 * g + j + c + 1] = (bf16)acc_w[t][j];
        __threadfence_block();

        // ---- assemble + online softmax (per-lane row q=c) ----
        float sA[4][4];
        #pragma unroll
        for (int t = 0; t < 4; ++t) {
            bf16x4 wv = *reinterpret_cast<const bf16x4*>(&win_lds[w][c][16 * t + 4 * g + 16]);
            float4 mv = *reinterpret_cast<const float4*>(&msk_lds[16 * t + 4 * g]);
            sA[t][0] = acc_s[t][0] + (float)wv[0] + mv.x;
            sA[t][1] = acc_s[t][1] + (float)wv[1] + mv.y;
            sA[t][2] = acc_s[t][2] + (float)wv[2] + mv.z;
            sA[t][3] = acc_s[t][3] + (float)wv[3] + mv.w;
        }
        float pm = sA[0][0];
        #pragma unroll
        for (int t = 0; t < 4; ++t)
            #pragma unroll
            for (int j = 0; j < 4; ++j) pm = fmaxf(pm, sA[t][j]);
        pm = fmaxf(pm, __shfl_xor(pm, 16));
        pm = fmaxf(pm, __shfl_xor(pm, 32));
        if (!__all(pm <= mrow + 8.0f)) {   // defer-max (THR=8)
            float mnew = fmaxf(mrow, pm);
            float alpha = exp2f((mrow - mnew) * L2E);
            mrow = mnew; lrow *= alpha;
            #pragma unroll
            for (int ot = 0; ot < 6; ++ot) acc_o[ot] *= alpha;
        }
        float rs = 0.f;
        #pragma unroll
        for (int t = 0; t < 4; ++t)
            #pragma unroll
            for (int j = 0; j < 4; ++j) {
                float p = exp2f((sA[t][j] - mrow) * L2E);
                sA[t][j] = p; rs += p;
            }
        rs += __shfl_xor(rs, 16);
        rs += __shfl_xor(rs, 32);
        lrow += rs;

        // ---- P -> LDS (col-major [q][k], aligned b64) ----
        #pragma unroll
        for (int t = 0; t < 4; ++t) {
            bf16x4 pk;
            #pragma unroll
            for (int j = 0; j < 4; ++j) pk[j] = (bf16)sA[t][j];
            *reinterpret_cast<bf16x4*>(&p_lds[w][c][16 * t + 4 * g]) = pk;
        }
        __threadfence_block();
        // ---- PV: O^T += V^T . P ----
        __builtin_amdgcn_s_setprio(1);
        #pragma unroll
        for (int ds = 0; ds < 2; ++ds) {
            bf16x8 pb_ = *reinterpret_cast<const bf16x8*>(&p_lds[w][c][32 * ds + 8 * g]);
            #pragma unroll
            for (int ot = 0; ot < 6; ++ot) {
                int rr = 16 * ot + c;
                bf16x8 a = *reinterpret_cast<const bf16x8*>(
                    &vt_lds[rr][((4 * ds + g) ^ (rr & 7)) * 8]);
                acc_o[ot] = mfma16(a, pb_, acc_o[ot]);
            }
        }
        __builtin_amdgcn_s_setprio(0);

        __syncthreads();   // all waves done reading this tile's LDS
        *reinterpret_cast<int4*>(kP0) = fK0;
        *reinterpret_cast<int4*>(kP1) = fK1;
        *reinterpret_cast<int4*>(kP2) = fK2;
        *reinterpret_cast<int4*>(vP0) = fV0;
        *reinterpret_cast<int4*>(vP1) = fV1;
        *reinterpret_cast<int4*>(vP2) = fV2;
        if (kt & 1) {
            *reinterpret_cast<int4*>(pPB0) = fP0;
            *reinterpret_cast<int4*>(pPB1) = fP1;
            *reinterpret_cast<int4*>(pPB2) = fP2;
        } else {
            *reinterpret_cast<int4*>(pPA0) = fP0;
            *reinterpret_cast<int4*>(pPA1) = fP1;
            *reinterpret_cast<int4*>(pPA2) = fP2;
        }
        if (tid < 64) msk_lds[tid] = (fM == 0) ? -1e30f : 0.f;
        __syncthreads();
    }

    // ---- epilogue ----
    float inv = 1.0f / lrow;
    size_t m = (size_t)b_ * TSEQ + q0 + 16 * w + c;
    bf16* ob = out + m * HID + h * HD + 4 * g;
    #pragma unroll
    for (int ot = 0; ot < 6; ++ot) {
        bf16x4 pk;
        #pragma unroll
        for (int j = 0; j < 4; ++j) pk[j] = (bf16)(acc_o[ot][j] * inv);
        *reinterpret_cast<bf16x4*>(&ob[16 * ot]) = pk;
    }
}

// ---------------- output projection ----------------
__launch_bounds__(256, 2)
__global__ void k_oproj(const bf16* __restrict__ A, const bf16* __restrict__ WT,
                        const float* __restrict__ bias, float* __restrict__ out) {
    __shared__ bf16 wt_lds[96][392];
    int m0 = blockIdx.x * 64, n0 = blockIdx.y * 96;
    int tid = threadIdx.x;
    #pragma unroll
    for (int s = 0; s < 18; ++s) {
        int cc = tid + 256 * s;
        int r = cc / 48, ch = cc % 48;
        *reinterpret_cast<int4*>(&wt_lds[r][ch * 8]) =
            *reinterpret_cast<const int4*>(WT + (size_t)(n0 + r) * HID + ch * 8);
    }
    __syncthreads();
    int lane = tid & 63, w = tid >> 6;
    int c = lane & 15, g = lane >> 4;
    const bf16* Abase = A + (size_t)(m0 + 16 * w + c) * HID + 8 * g;
    f32x4 acc[6] = {};
    for (int ks = 0; ks < 12; ++ks) {
        bf16x8 a = *reinterpret_cast<const bf16x8*>(Abase + 32 * ks);
        #pragma unroll
        for (int jt = 0; jt < 6; ++jt) {
            bf16x8 b = *reinterpret_cast<const bf16x8*>(&wt_lds[16 * jt + c][32 * ks + 8 * g]);
            acc[jt] = mfma16(a, b, acc[jt]);
        }
    }
    int rbase = m0 + 16 * w + 4 * g;
    #pragma unroll
    for (int jt = 0; jt < 6; ++jt) {
        int n = n0 + 16 * jt + c;
        float bb = bias[n];
        #pragma unroll
        for (int j = 0; j < 4; ++j)
            out[(size_t)(rbase + j) * HID + n] = acc[jt][j] + bb;
    }
}

extern "C" void kernel_launch(void* const* d_in, const int* in_sizes, int n_in,
                              void* d_out, int out_size, void* d_ws, size_t ws_size,
                              hipStream_t stream) {
    const float* hs  = (const float*)d_in[0];
    const float* pe  = (const float*)d_in[1];
    const int*   msk = (const int*)d_in[2];
    const float* Wq  = (const float*)d_in[3];
    const float* bq  = (const float*)d_in[4];
    const float* Wk  = (const float*)d_in[5];
    const float* bk  = (const float*)d_in[6];
    const float* Wv  = (const float*)d_in[7];
    const float* bv  = (const float*)d_in[8];
    const float* Wo  = (const float*)d_in[9];
    const float* bo  = (const float*)d_in[10];
    const float* Wp  = (const float*)d_in[11];
    const float* pbu = (const float*)d_in[12];
    const float* pbv = (const float*)d_in[13];

    char* ws = (char*)d_ws;
    size_t off = 0;
    auto alloc = [&](size_t b) { char* p = ws + off; off += (b + 255) & ~(size_t)255; return p; };
    bf16* Xb  = (bf16*)alloc((size_t)16384 * HID * 2);
    bf16* Pb  = (bf16*)alloc((size_t)4096 * HID * 2);
    bf16* wqT = (bf16*)alloc((size_t)HID * HID * 2);
    bf16* wkT = (bf16*)alloc((size_t)HID * HID * 2);
    bf16* wvT = (bf16*)alloc((size_t)HID * HID * 2);
    bf16* woT = (bf16*)alloc((size_t)HID * HID * 2);
    bf16* wpT = (bf16*)alloc((size_t)HID * HID * 2);
    bf16* qu  = (bf16*)alloc((size_t)NBATCH * NHEAD * TSEQ * HD * 2);
    bf16* qv  = (bf16*)alloc((size_t)NBATCH * NHEAD * TSEQ * HD * 2);
    bf16* kws = (bf16*)alloc((size_t)NBATCH * NHEAD * TSEQ * HD * 2);
    bf16* vt  = (bf16*)alloc((size_t)NBATCH * NHEAD * TSEQ * HD * 2);
    bf16* pp  = (bf16*)alloc((size_t)NHEAD * 4096 * HD * 2);
    bf16* ao  = (bf16*)alloc((size_t)16384 * HID * 2);

    k_conv8<<<3072, 256, 0, stream>>>(hs, Xb, 786432);
    k_conv8<<<768, 256, 0, stream>>>(pe, Pb, 196560);
    k_convT<<<576, 256, 0, stream>>>(Wq, wqT);
    k_convT<<<576, 256, 0, stream>>>(Wk, wkT);
    k_convT<<<576, 256, 0, stream>>>(Wv, wvT);
    k_convT<<<576, 256, 0, stream>>>(Wo, woT);
    k_convT<<<576, 256, 0, stream>>>(Wp, wpT);
    k_proj<<<dim3(256, 4, 4), 256, 0, stream>>>(Xb, Pb, wqT, wkT, wvT, wpT,
                                                bq, bk, bv, pbu, pbv,
                                                qu, qv, kws, vt, pp);
    k_attn<<<1024, 256, 0, stream>>>(qu, qv, kws, vt, pp, msk, ao);
    k_oproj<<<dim3(256, 4), 256, 0, stream>>>(ao, woT, bo, (float*)d_out);
}